// Round 6
// baseline (336.082 us; speedup 1.0000x reference)
//
#include <hip/hip_runtime.h>
#include <stdint.h>

#define S_LEN 2048
#define EMBED 2048
#define NHEADS 16
#define HDIM 128

typedef __attribute__((ext_vector_type(8))) short bf16x8;
typedef __attribute__((ext_vector_type(4))) float f32x4;
typedef unsigned short us;

static __device__ __forceinline__ us f2b(float f) {
    union { float f; unsigned u; } x; x.f = f;
    unsigned r = x.u + 0x7fffu + ((x.u >> 16) & 1u);
    return (us)(r >> 16);
}

// packed f32x2 -> bf16x2 (RNE, single HW instruction)
static __device__ __forceinline__ unsigned cvtpk(float a, float b) {
    unsigned r;
    asm("v_cvt_pk_bf16_f32 %0, %1, %2" : "=v"(r) : "v"(a), "v"(b));
    return r;
}

static __device__ __forceinline__ uint2 pack4(float a, float b, float c, float d) {
    uint2 u;
    u.x = cvtpk(a, b);
    u.y = cvtpk(c, d);
    return u;
}

// 2^x via v_exp_f32
static __device__ __forceinline__ float fexp2(float x) {
    float r;
    asm("v_exp_f32 %0, %1" : "=v"(r) : "v"(x));
    return r;
}

// async 16B global->LDS; lds dest wave-uniform base, HW adds lane*16
static __device__ __forceinline__ void gl_lds16(const void* g, void* l) {
    __builtin_amdgcn_global_load_lds(
        (const __attribute__((address_space(1))) void*)g,
        (__attribute__((address_space(3))) void*)l, 16, 0, 0);
}

// ---------------------------------------------------------------------------
// GEMM building blocks: 128x128 tile, BK=64, LDS [row][64k] with 16B-chunk
// XOR swizzle (phys_chunk = logical_chunk ^ (row&7)); 4 waves in 2x2.
// SINGLE-buffered (m97 structure): 32KB LDS -> 4 blocks/CU; cross-block wave
// slip provides the pipelining (measured better than explicit dbuf at 2/CU).

// stage a 128x64 bf16 tile via DMA (16KB, 4 gl_lds per thread-slot pass)
static __device__ __forceinline__ void dma_tile(const us* __restrict__ g, int k0,
                                                us* dst, int tid) {
#pragma unroll
    for (int i = 0; i < 4; i++) {
        int sl = i * 256 + tid;
        int row = sl >> 3, cp = sl & 7, c = cp ^ (row & 7);
        gl_lds16(g + (size_t)row * 2048 + k0 + c * 8,
                 (char*)dst + (i * 256 + (tid & 192)) * 16);
    }
}

static __device__ __forceinline__ void loadA_f32(const float* __restrict__ g,
                                                 float4 pf[8]) {
#pragma unroll
    for (int i = 0; i < 8; i++) pf[i] = ((const float4*)g)[i];
}

static __device__ __forceinline__ void writeA_f32(us* dst, const float4 pf[8],
                                                  int row, int h) {
#pragma unroll
    for (int cc = 0; cc < 4; cc++) {
        int p = (h * 4 + cc) ^ (row & 7);
        float4 a = pf[cc * 2], b = pf[cc * 2 + 1];
        uint4 u;
        u.x = (unsigned)f2b(a.x) | ((unsigned)f2b(a.y) << 16);
        u.y = (unsigned)f2b(a.z) | ((unsigned)f2b(a.w) << 16);
        u.z = (unsigned)f2b(b.x) | ((unsigned)f2b(b.y) << 16);
        u.w = (unsigned)f2b(b.z) | ((unsigned)f2b(b.w) << 16);
        *(uint4*)&dst[row * 64 + p * 8] = u;
    }
}

static __device__ __forceinline__ void frag_mfma(const us* curA, const us* curB,
                                                 int wm, int wn, int lm, int quad,
                                                 f32x4 acc[4][4]) {
#pragma unroll
    for (int kc = 0; kc < 2; kc++) {
        bf16x8 af[4], bfr[4];
#pragma unroll
        for (int mi = 0; mi < 4; mi++) {
            int row = wm * 64 + mi * 16 + lm;
            int p = (kc * 4 + quad) ^ (row & 7);
            af[mi] = *(const bf16x8*)&curA[row * 64 + p * 8];
        }
#pragma unroll
        for (int ni = 0; ni < 4; ni++) {
            int row = wn * 64 + ni * 16 + lm;
            int p = (kc * 4 + quad) ^ (row & 7);
            bfr[ni] = *(const bf16x8*)&curB[row * 64 + p * 8];
        }
#pragma unroll
        for (int mi = 0; mi < 4; mi++)
#pragma unroll
            for (int ni = 0; ni < 4; ni++)
                acc[mi][ni] = __builtin_amdgcn_mfma_f32_16x16x32_bf16(
                    af[mi], bfr[ni], acc[mi][ni], 0, 0, 0);
    }
}

// ---------------------------------------------------------------------------
// tcast3: Wq/Wk/Wv f32 [k][n] -> bf16 [n][k]; blocks >= 2304 cast query f32 ->
// bf16 row-major (qbf) so proj_qkv's Q path can be pure-DMA.
__global__ void tcast3(const float* __restrict__ Wq, const float* __restrict__ Wk,
                       const float* __restrict__ Wv, const float* __restrict__ query,
                       us* __restrict__ Wqt, us* __restrict__ Wkvt,
                       us* __restrict__ qbf) {
    int b = blockIdx.x;
    if (b >= 2304) {
        // straight cast: 8 contiguous f32 -> 8 bf16 per thread
        int id = (b - 2304) * 256 + threadIdx.x;   // [0, 1048576)
        const float4* in4 = (const float4*)query;
        float4 a = in4[id * 2], c = in4[id * 2 + 1];
        uint4 u;
        u.x = (unsigned)f2b(a.x) | ((unsigned)f2b(a.y) << 16);
        u.y = (unsigned)f2b(a.z) | ((unsigned)f2b(a.w) << 16);
        u.z = (unsigned)f2b(c.x) | ((unsigned)f2b(c.y) << 16);
        u.w = (unsigned)f2b(c.z) | ((unsigned)f2b(c.w) << 16);
        ((uint4*)qbf)[id] = u;
        return;
    }
    const float* in; us* out; int N, rel;
    if (b < 2048)      { in = Wq; out = Wqt;  N = 2048; rel = b; }
    else if (b < 2176) { in = Wk; out = Wkvt; N = 128;  rel = b - 2048; }
    else               { in = Wv; out = Wkvt + (size_t)128 * 2048; N = 128; rel = b - 2176; }
    int id = rel * 256 + threadIdx.x;
    int n = id & (N - 1), k0 = (id / N) * 8;
    us t8[8];
#pragma unroll
    for (int j = 0; j < 8; j++) t8[j] = f2b(in[(size_t)(k0 + j) * N + n]);
    *(uint4*)&out[(size_t)n * 2048 + k0] = *(uint4*)t8;
}

// ---------------------------------------------------------------------------
// fused Q + KV(split-K 4) projection. blocks [0,512): Q tiles (pure-DMA bf16
// A from qbf); [512,768): KV (f32 reg-staged A). Single-buffered 32KB LDS,
// 4 blocks/CU. Q epilogue folds attention scale * log2(e) into Qh.
__global__ __launch_bounds__(256, 4) void proj_qkv(
    const float* __restrict__ key, const float* __restrict__ value,
    const us* __restrict__ qbf, const us* __restrict__ Wqt,
    const us* __restrict__ Wkvt, const float* __restrict__ bq,
    us* __restrict__ Qh, float* __restrict__ part)
{
    __shared__ __align__(16) us A0[128 * 64];
    __shared__ __align__(16) us B0[128 * 64];

    const int tid = threadIdx.x;
    const int lane = tid & 63, w = tid >> 6, lm = lane & 15, quad = lane >> 4;
    const int wm = w >> 1, wn = w & 1;
    const int id = blockIdx.x;
    // 1/sqrt(128) * log2(e)
    const float CQ = 0.12751743150179665f;

    f32x4 acc[4][4];
#pragma unroll
    for (int i = 0; i < 4; i++)
#pragma unroll
        for (int j = 0; j < 4; j++) acc[i][j] = (f32x4){0.f, 0.f, 0.f, 0.f};

    if (id < 512) {
        // ---- Q projection: pure-DMA single-buffered GEMM ----
        const int bn = (id & 15) * 128, bm = (id >> 4) * 128;
        const us* Atile = qbf + (size_t)bm * 2048;
        const us* Btile = Wqt + (size_t)bn * 2048;

        for (int kk = 0; kk < 32; kk++) {
            __syncthreads();                       // buffer free
            dma_tile(Atile, kk * 64, A0, tid);
            dma_tile(Btile, kk * 64, B0, tid);
            __syncthreads();                       // drain + publish
            frag_mfma(A0, B0, wm, wn, lm, quad, acc);
        }

#pragma unroll
        for (int mi = 0; mi < 4; mi++)
#pragma unroll
            for (int ni = 0; ni < 4; ni++) {
                int col = bn + wn * 64 + ni * 16 + lm;
                float bv = bq[col];
#pragma unroll
                for (int r = 0; r < 4; r++) {
                    int row = bm + wm * 64 + mi * 16 + quad * 4 + r;
                    float v = (acc[mi][ni][r] + bv) * CQ;
                    int b = row >> 11, s = row & 2047;
                    int hh = col >> 7, hd = col & 127;
                    size_t addr = (((size_t)(b * 16 + hh) * 2048 + s) << 7)
                                  + (((hd >> 3) ^ (s & 7)) << 3) + (hd & 7);
                    Qh[addr] = f2b(v);
                }
            }
    } else {
        // ---- KV projection: split-K 4, f32 reg-staged A, single-buffer ----
        int e = id - 512;
        int z = e >> 6, r = e & 63, isV = r & 1;
        int bm = (r >> 1) * 128, bn = isV * 128;
        const float* Atile = (isV ? value : key) + (size_t)bm * 2048;
        const us* Btile = Wkvt + (size_t)bn * 2048;
        const int kbeg = z * 512;
        const int arow = tid >> 1, h = tid & 1;
        const float* Ag = Atile + (size_t)arow * 2048 + h * 32;

        for (int kk = 0; kk < 8; kk++) {
            float4 pf[8];
            loadA_f32(Ag + kbeg + kk * 64, pf);    // overlaps prev MFMA phase
            __syncthreads();                       // buffer free
            writeA_f32(A0, pf, arow, h);
            dma_tile(Btile, kbeg + kk * 64, B0, tid);
            __syncthreads();                       // drain + publish
            frag_mfma(A0, B0, wm, wn, lm, quad, acc);
        }

        float* pp = part + (size_t)z * 1048576;
#pragma unroll
        for (int mi = 0; mi < 4; mi++)
#pragma unroll
            for (int ni = 0; ni < 4; ni++) {
                int col = bn + wn * 64 + ni * 16 + lm;
#pragma unroll
                for (int r = 0; r < 4; r++) {
                    int row = bm + wm * 64 + mi * 16 + quad * 4 + r;
                    pp[(size_t)row * 256 + col] = acc[mi][ni][r];
                }
            }
    }
}

// ---------------------------------------------------------------------------
// finish_wot: blocks [0,2048) transpose+cast Wo; [2048,6144) kv split-K reduce
__global__ void finish_wot(const float* __restrict__ part, const float* __restrict__ bk,
                           const float* __restrict__ bv, us* __restrict__ Kb,
                           us* __restrict__ Vt, const float* __restrict__ Wo,
                           us* __restrict__ Wot) {
    int b = blockIdx.x;
    if (b < 2048) {
        int id = b * 256 + threadIdx.x;
        int n = id & 2047, k0 = (id >> 11) * 8;
        us t8[8];
#pragma unroll
        for (int j = 0; j < 8; j++) t8[j] = f2b(Wo[(size_t)(k0 + j) * 2048 + n]);
        *(uint4*)&Wot[(size_t)n * 2048 + k0] = *(uint4*)t8;
    } else {
        int id = (b - 2048) * 256 + threadIdx.x;
        int row = id >> 8, n = id & 255;
        float s = part[id] + part[1048576 + id] + part[2097152 + id] + part[3145728 + id];
        int bb = row >> 11, t = row & 2047;
        if (n < 128) {
            int hd = n;
            s += bk[hd];
            Kb[((size_t)(bb * 2048 + t) << 7) + (((hd >> 3) ^ (t & 7)) << 3) + (hd & 7)] = f2b(s);
        } else {
            int hd = n - 128;
            s += bv[hd];
            size_t addr = (((size_t)(bb * 64 + (t >> 5)) * 128 + hd) << 5)
                          + ((((t >> 3) & 3) ^ ((hd >> 1) & 3)) << 3) + (t & 7);
            Vt[addr] = f2b(s);
        }
    }
}

// ---------------------------------------------------------------------------
// MQA flash attention v5: QBLK=128 (512 blocks, 2/CU), 4 waves 2x2.
// K direct-from-global with register prefetch; loop unrolled x2 so the
// prefetch buffers are statically named (no register rotation). V LDS
// double-buffered via gl_lds; Ps double-buffered; one barrier per iteration.
__global__ __launch_bounds__(256, 2) void mqa_attn(
    const us* __restrict__ Qh, const us* __restrict__ Kb,
    const us* __restrict__ Vt, us* __restrict__ AO)
{
    __shared__ __align__(16) char smem[33792];
    us* Ps  = (us*)smem;                 // [0,16K): 2 x 8KB
    us* Vts = (us*)(smem + 16384);       // [16K,32K): 2 x 8KB
    float* Lb = (float*)(smem + 32768);  // [32K,33K): 256 floats

    const int tid  = threadIdx.x;
    const int lane = tid & 63;
    const int w    = tid >> 6;
    const int lm   = lane & 15;
    const int quad = lane >> 4;
    const int wm = w >> 1, wn = w & 1;   // wm: t/hd half, wn: q half (64 rows)
    const int q0 = blockIdx.x * 128;
    const int h  = blockIdx.y;
    const int b  = blockIdx.z;

    const us* Qtile = Qh + (((size_t)(b * 16 + h) * 2048 + q0) << 7);
    const us* Kbase = Kb + ((size_t)b * 2048 << 7);
    const us* Vbase = Vt + (size_t)b * 64 * 4096;

    // stage V(0) tile (8KB, 512 slots, 2 per thread)
#pragma unroll
    for (int i = 0; i < 2; i++) {
        int sl = w * 128 + i * 64 + lane;
        gl_lds16(Vbase + sl * 8, (char*)Vts + (w * 128 + i * 64) * 16);
    }

    // Q fragments direct from global (swizzled layout preserved by proj)
    bf16x8 qf[4][4];
#pragma unroll
    for (int nt = 0; nt < 4; nt++)
#pragma unroll
        for (int ks = 0; ks < 4; ks++) {
            int q = wn * 64 + nt * 16 + lm;
            int cp = (ks * 4 + quad) ^ (q & 7);
            qf[nt][ks] = *(const bf16x8*)&Qtile[q * 128 + cp * 8];
        }

    // K fragments for it=0, direct from global
    const int trow = wm * 16 + lm;       // wave's K row within 32-row tile
    bf16x8 kfA[4], kfB[4];
#pragma unroll
    for (int ks = 0; ks < 4; ks++) {
        int cp = (ks * 4 + quad) ^ (lm & 7);
        kfA[ks] = *(const bf16x8*)&Kbase[(size_t)trow * 128 + cp * 8];
    }

    __syncthreads();   // V(0) drained (also waits qf/kf loads)

    f32x4 oacc[4][4];
#pragma unroll
    for (int i = 0; i < 4; i++)
#pragma unroll
        for (int j = 0; j < 4; j++) oacc[i][j] = (f32x4){0.f, 0.f, 0.f, 0.f};
    float lsum[4] = {0.f, 0.f, 0.f, 0.f};

    auto attn_iter = [&](int it, int p, bf16x8 (&kfc)[4], bf16x8 (&kfn)[4]) {
        // K register-prefetch for it+1 (consumed next call; ~full iteration
        // of latency cover, no rotation copy needed)
        if (it < 63) {
            const us* kg = Kbase + (size_t)(it + 1) * 4096 + (size_t)trow * 128;
#pragma unroll
            for (int ks = 0; ks < 4; ks++) {
                int cp = (ks * 4 + quad) ^ (lm & 7);
                kfn[ks] = *(const bf16x8*)&kg[cp * 8];
            }
        }

        // QK^T with current K fragments (pure register)
        f32x4 sacc[4];
#pragma unroll
        for (int nt = 0; nt < 4; nt++) sacc[nt] = (f32x4){0.f, 0.f, 0.f, 0.f};
        __builtin_amdgcn_s_setprio(1);
#pragma unroll
        for (int ks = 0; ks < 4; ks++) {
#pragma unroll
            for (int nt = 0; nt < 4; nt++)
                sacc[nt] = __builtin_amdgcn_mfma_f32_16x16x32_bf16(
                    kfc[ks], qf[nt][ks], sacc[nt], 0, 0, 0);
        }
        __builtin_amdgcn_s_setprio(0);

        // softmax (scale pre-folded into Q) -> Ps[p]
        us* Pw = Ps + p * 4096;
#pragma unroll
        for (int nt = 0; nt < 4; nt++) {
            int q = wn * 64 + nt * 16 + lm;
            float p0 = fexp2(sacc[nt][0]);
            float p1 = fexp2(sacc[nt][1]);
            float p2 = fexp2(sacc[nt][2]);
            float p3 = fexp2(sacc[nt][3]);
            lsum[nt] += (p0 + p1) + (p2 + p3);
            int tb = wm * 16 + quad * 4;
            int cp = (tb >> 3) ^ ((q >> 1) & 3);
            *(uint2*)&Pw[q * 32 + cp * 8 + (tb & 7)] = pack4(p0, p1, p2, p3);
        }

        __syncthreads();   // Ps[p] published; V prefetch (prev iter) drained

        // V prefetch for it+1 into Vts[1-p]
        if (it < 63) {
            const us* vg = Vbase + (it + 1) * 4096;
#pragma unroll
            for (int i = 0; i < 2; i++) {
                int sl = w * 128 + i * 64 + lane;
                gl_lds16(vg + sl * 8, (char*)Vts + (1 - p) * 8192 + (w * 128 + i * 64) * 16);
            }
        }

        const us* Vst = Vts + p * 4096;
        const us* Pr = Ps + p * 4096;
        bf16x8 vf[4], pfr[4];
#pragma unroll
        for (int mt = 0; mt < 4; mt++) {
            int hd = (wm * 4 + mt) * 16 + lm;
            int cp = quad ^ ((hd >> 1) & 3);
            vf[mt] = *(const bf16x8*)&Vst[hd * 32 + cp * 8];
        }
#pragma unroll
        for (int nt = 0; nt < 4; nt++) {
            int q = (wn * 4 + nt) * 16 + lm;
            int cp = quad ^ ((q >> 1) & 3);
            pfr[nt] = *(const bf16x8*)&Pr[q * 32 + cp * 8];
        }
        __builtin_amdgcn_s_setprio(1);
#pragma unroll
        for (int mt = 0; mt < 4; mt++)
#pragma unroll
            for (int nt = 0; nt < 4; nt++)
                oacc[mt][nt] = __builtin_amdgcn_mfma_f32_16x16x32_bf16(
                    vf[mt], pfr[nt], oacc[mt][nt], 0, 0, 0);
        __builtin_amdgcn_s_setprio(0);
    };

    for (int it = 0; it < 64; it += 2) {
        attn_iter(it, 0, kfA, kfB);
        attn_iter(it + 1, 1, kfB, kfA);
    }

#pragma unroll
    for (int nt = 0; nt < 4; nt++) {
        lsum[nt] += __shfl_xor(lsum[nt], 16);
        lsum[nt] += __shfl_xor(lsum[nt], 32);
    }
    if (quad == 0) {
#pragma unroll
        for (int nt = 0; nt < 4; nt++)
            Lb[wm * 128 + wn * 64 + nt * 16 + lm] = lsum[nt];
    }
    __syncthreads();

#pragma unroll
    for (int nt = 0; nt < 4; nt++) {
        int q = (wn * 4 + nt) * 16 + lm;
        float linv = 1.f / (Lb[q] + Lb[128 + q]);
#pragma unroll
        for (int mt = 0; mt < 4; mt++) {
            int hdb = (wm * 4 + mt) * 16 + quad * 4;
            uint2 u = pack4(oacc[mt][nt][0] * linv, oacc[mt][nt][1] * linv,
                            oacc[mt][nt][2] * linv, oacc[mt][nt][3] * linv);
            *(uint2*)&AO[((size_t)(b * 2048 + q0 + q)) * 2048 + h * 128 + hdb] = u;
        }
    }
}

// ---------------------------------------------------------------------------
// output projection: AO bf16 @ Wot^T + bo -> f32, single-buffered pure-DMA,
// 4 blocks/CU
__global__ __launch_bounds__(256, 4) void oproj(
    const us* __restrict__ AO, const us* __restrict__ Wot,
    const float* __restrict__ bo, float* __restrict__ out)
{
    __shared__ __align__(16) us A0[128 * 64];
    __shared__ __align__(16) us B0[128 * 64];

    const int tid = threadIdx.x;
    const int lane = tid & 63, w = tid >> 6, lm = lane & 15, quad = lane >> 4;
    const int wm = w >> 1, wn = w & 1;
    const int bn = blockIdx.x * 128, bm = blockIdx.y * 128;
    const us* Atile = AO + (size_t)bm * 2048;
    const us* Btile = Wot + (size_t)bn * 2048;

    f32x4 acc[4][4];
#pragma unroll
    for (int i = 0; i < 4; i++)
#pragma unroll
        for (int j = 0; j < 4; j++) acc[i][j] = (f32x4){0.f, 0.f, 0.f, 0.f};

    for (int kk = 0; kk < 32; kk++) {
        __syncthreads();                       // buffer free
        dma_tile(Atile, kk * 64, A0, tid);
        dma_tile(Btile, kk * 64, B0, tid);
        __syncthreads();                       // drain + publish
        frag_mfma(A0, B0, wm, wn, lm, quad, acc);
    }

#pragma unroll
    for (int mi = 0; mi < 4; mi++)
#pragma unroll
        for (int ni = 0; ni < 4; ni++) {
            int col = bn + wn * 64 + ni * 16 + lm;
            float bv = bo[col];
#pragma unroll
            for (int r = 0; r < 4; r++) {
                int row = bm + wm * 64 + mi * 16 + quad * 4 + r;
                out[(size_t)row * 2048 + col] = acc[mi][ni][r] + bv;
            }
        }
}

// ---------------------------------------------------------------------------
extern "C" void kernel_launch(void* const* d_in, const int* in_sizes, int n_in,
                              void* d_out, int out_size, void* d_ws, size_t ws_size,
                              hipStream_t stream) {
    const float* query = (const float*)d_in[0];
    const float* key   = (const float*)d_in[1];
    const float* value = (const float*)d_in[2];
    const float* Wq = (const float*)d_in[3];
    const float* bq = (const float*)d_in[4];
    const float* Wk = (const float*)d_in[5];
    const float* bk = (const float*)d_in[6];
    const float* Wv = (const float*)d_in[7];
    const float* bv = (const float*)d_in[8];
    const float* Wo = (const float*)d_in[9];
    const float* bo = (const float*)d_in[10];
    float* out = (float*)d_out;

    char* ws = (char*)d_ws;
    us*    Wqt  = (us*)ws;                  //  8.39MB (reused for Wot)
    us*    Wot  = Wqt;
    us*    Wkvt = (us*)(ws + 8388608);      //  1.05MB
    us*    Qh   = (us*)(ws + 9437184);      // 16.78MB
    float* part = (float*)(ws + 26214400);  // 16.78MB (reused for AO)
    us*    AO   = (us*)part;
    us*    Kb   = (us*)(ws + 42991616);     //  1.05MB
    us*    Vtb  = (us*)(ws + 44040192);     //  1.05MB
    us*    qbf  = (us*)(ws + 45088768);     // 16.78MB bf16 query (row-major)

    dim3 blk(256);
    tcast3<<<6400, blk, 0, stream>>>(Wq, Wk, Wv, query, Wqt, Wkvt, qbf);
    proj_qkv<<<768, blk, 0, stream>>>(key, value, qbf, Wqt, Wkvt, bq, Qh, part);
    finish_wot<<<6144, blk, 0, stream>>>(part, bk, bv, Kb, Vtb, Wo, Wot);
    mqa_attn<<<dim3(16, 16, 2), blk, 0, stream>>>(Qh, Kb, Vtb, AO);
    oproj<<<dim3(16, 32), blk, 0, stream>>>(AO, Wot, bo, out);
}

// Round 8
// 327.823 us; speedup vs baseline: 1.0252x; 1.0252x over previous
//
#include <hip/hip_runtime.h>
#include <stdint.h>

#define S_LEN 2048
#define EMBED 2048
#define NHEADS 16
#define HDIM 128

typedef __attribute__((ext_vector_type(8))) short bf16x8;
typedef __attribute__((ext_vector_type(4))) float f32x4;
typedef unsigned short us;

static __device__ __forceinline__ us f2b(float f) {
    union { float f; unsigned u; } x; x.f = f;
    unsigned r = x.u + 0x7fffu + ((x.u >> 16) & 1u);
    return (us)(r >> 16);
}

// packed f32x2 -> bf16x2 (RNE, single HW instruction)
static __device__ __forceinline__ unsigned cvtpk(float a, float b) {
    unsigned r;
    asm("v_cvt_pk_bf16_f32 %0, %1, %2" : "=v"(r) : "v"(a), "v"(b));
    return r;
}

static __device__ __forceinline__ uint2 pack4(float a, float b, float c, float d) {
    uint2 u;
    u.x = cvtpk(a, b);
    u.y = cvtpk(c, d);
    return u;
}

// 2^x via v_exp_f32
static __device__ __forceinline__ float fexp2(float x) {
    float r;
    asm("v_exp_f32 %0, %1" : "=v"(r) : "v"(x));
    return r;
}

// async 16B global->LDS; lds dest wave-uniform base, HW adds lane*16
static __device__ __forceinline__ void gl_lds16(const void* g, void* l) {
    __builtin_amdgcn_global_load_lds(
        (const __attribute__((address_space(1))) void*)g,
        (__attribute__((address_space(3))) void*)l, 16, 0, 0);
}

// ---------------------------------------------------------------------------
// GEMM building blocks: 128x128 tile, BK=64, LDS [row][64k] with 16B-chunk
// XOR swizzle (phys_chunk = logical_chunk ^ (row&7)); 4 waves in 2x2.
// SINGLE-buffered (m97 structure): 32KB LDS; grids are 512-768 blocks so
// occupancy is grid-limited (2-3 blocks/CU) either way.

// stage a 128x64 bf16 tile via DMA (16KB, 4 gl_lds per thread-slot pass)
static __device__ __forceinline__ void dma_tile(const us* __restrict__ g, int k0,
                                                us* dst, int tid) {
#pragma unroll
    for (int i = 0; i < 4; i++) {
        int sl = i * 256 + tid;
        int row = sl >> 3, cp = sl & 7, c = cp ^ (row & 7);
        gl_lds16(g + (size_t)row * 2048 + k0 + c * 8,
                 (char*)dst + (i * 256 + (tid & 192)) * 16);
    }
}

static __device__ __forceinline__ void loadA_f32(const float* __restrict__ g,
                                                 float4 pf[8]) {
#pragma unroll
    for (int i = 0; i < 8; i++) pf[i] = ((const float4*)g)[i];
}

static __device__ __forceinline__ void writeA_f32(us* dst, const float4 pf[8],
                                                  int row, int h) {
#pragma unroll
    for (int cc = 0; cc < 4; cc++) {
        int p = (h * 4 + cc) ^ (row & 7);
        float4 a = pf[cc * 2], b = pf[cc * 2 + 1];
        uint4 u;
        u.x = (unsigned)f2b(a.x) | ((unsigned)f2b(a.y) << 16);
        u.y = (unsigned)f2b(a.z) | ((unsigned)f2b(a.w) << 16);
        u.z = (unsigned)f2b(b.x) | ((unsigned)f2b(b.y) << 16);
        u.w = (unsigned)f2b(b.z) | ((unsigned)f2b(b.w) << 16);
        *(uint4*)&dst[row * 64 + p * 8] = u;
    }
}

static __device__ __forceinline__ void frag_mfma(const us* curA, const us* curB,
                                                 int wm, int wn, int lm, int quad,
                                                 f32x4 acc[4][4]) {
#pragma unroll
    for (int kc = 0; kc < 2; kc++) {
        bf16x8 af[4], bfr[4];
#pragma unroll
        for (int mi = 0; mi < 4; mi++) {
            int row = wm * 64 + mi * 16 + lm;
            int p = (kc * 4 + quad) ^ (row & 7);
            af[mi] = *(const bf16x8*)&curA[row * 64 + p * 8];
        }
#pragma unroll
        for (int ni = 0; ni < 4; ni++) {
            int row = wn * 64 + ni * 16 + lm;
            int p = (kc * 4 + quad) ^ (row & 7);
            bfr[ni] = *(const bf16x8*)&curB[row * 64 + p * 8];
        }
#pragma unroll
        for (int mi = 0; mi < 4; mi++)
#pragma unroll
            for (int ni = 0; ni < 4; ni++)
                acc[mi][ni] = __builtin_amdgcn_mfma_f32_16x16x32_bf16(
                    af[mi], bfr[ni], acc[mi][ni], 0, 0, 0);
    }
}

// ---------------------------------------------------------------------------
// tcast3: Wq/Wk/Wv f32 [k][n] -> bf16 [n][k]; blocks >= 2304 cast query f32 ->
// bf16 row-major (qbf) so proj_qkv's Q path can be pure-DMA.
__global__ void tcast3(const float* __restrict__ Wq, const float* __restrict__ Wk,
                       const float* __restrict__ Wv, const float* __restrict__ query,
                       us* __restrict__ Wqt, us* __restrict__ Wkvt,
                       us* __restrict__ qbf) {
    int b = blockIdx.x;
    if (b >= 2304) {
        // straight cast: 8 contiguous f32 -> 8 bf16 per thread
        int id = (b - 2304) * 256 + threadIdx.x;   // [0, 1048576)
        const float4* in4 = (const float4*)query;
        float4 a = in4[id * 2], c = in4[id * 2 + 1];
        uint4 u;
        u.x = (unsigned)f2b(a.x) | ((unsigned)f2b(a.y) << 16);
        u.y = (unsigned)f2b(a.z) | ((unsigned)f2b(a.w) << 16);
        u.z = (unsigned)f2b(c.x) | ((unsigned)f2b(c.y) << 16);
        u.w = (unsigned)f2b(c.z) | ((unsigned)f2b(c.w) << 16);
        ((uint4*)qbf)[id] = u;
        return;
    }
    const float* in; us* out; int N, rel;
    if (b < 2048)      { in = Wq; out = Wqt;  N = 2048; rel = b; }
    else if (b < 2176) { in = Wk; out = Wkvt; N = 128;  rel = b - 2048; }
    else               { in = Wv; out = Wkvt + (size_t)128 * 2048; N = 128; rel = b - 2176; }
    int id = rel * 256 + threadIdx.x;
    int n = id & (N - 1), k0 = (id / N) * 8;
    us t8[8];
#pragma unroll
    for (int j = 0; j < 8; j++) t8[j] = f2b(in[(size_t)(k0 + j) * N + n]);
    *(uint4*)&out[(size_t)n * 2048 + k0] = *(uint4*)t8;
}

// ---------------------------------------------------------------------------
// fused Q + KV(split-K 4) projection. blocks [0,512): Q tiles (pure-DMA bf16
// A from qbf, XCD-chunked tile mapping); [512,768): KV (f32 reg-staged A).
// Single-buffered 32KB LDS. Q epilogue folds attention scale*log2(e) into Qh.
__global__ __launch_bounds__(256, 4) void proj_qkv(
    const float* __restrict__ key, const float* __restrict__ value,
    const us* __restrict__ qbf, const us* __restrict__ Wqt,
    const us* __restrict__ Wkvt, const float* __restrict__ bq,
    us* __restrict__ Qh, float* __restrict__ part)
{
    __shared__ __align__(16) us A0[128 * 64];
    __shared__ __align__(16) us B0[128 * 64];

    const int tid = threadIdx.x;
    const int lane = tid & 63, w = tid >> 6, lm = lane & 15, quad = lane >> 4;
    const int wm = w >> 1, wn = w & 1;
    const int id = blockIdx.x;
    // 1/sqrt(128) * log2(e)
    const float CQ = 0.12751743150179665f;

    f32x4 acc[4][4];
#pragma unroll
    for (int i = 0; i < 4; i++)
#pragma unroll
        for (int j = 0; j < 4; j++) acc[i][j] = (f32x4){0.f, 0.f, 0.f, 0.f};

    if (id < 512) {
        // ---- Q projection: pure-DMA single-buffered GEMM ----
        // XCD-chunked remap: 64 consecutive tiles per XCD (4 A-row panels,
        // 2MB, L2-resident per XCD). 512 % 8 == 0 -> bijective (1-D grid).
        const int nid = (id & 7) * 64 + (id >> 3);
        const int bn = (nid & 15) * 128, bm = (nid >> 4) * 128;
        const us* Atile = qbf + (size_t)bm * 2048;
        const us* Btile = Wqt + (size_t)bn * 2048;

        for (int kk = 0; kk < 32; kk++) {
            __syncthreads();                       // buffer free
            dma_tile(Atile, kk * 64, A0, tid);
            dma_tile(Btile, kk * 64, B0, tid);
            __syncthreads();                       // drain + publish
            frag_mfma(A0, B0, wm, wn, lm, quad, acc);
        }

#pragma unroll
        for (int mi = 0; mi < 4; mi++)
#pragma unroll
            for (int ni = 0; ni < 4; ni++) {
                int col = bn + wn * 64 + ni * 16 + lm;
                float bv = bq[col];
#pragma unroll
                for (int r = 0; r < 4; r++) {
                    int row = bm + wm * 64 + mi * 16 + quad * 4 + r;
                    float v = (acc[mi][ni][r] + bv) * CQ;
                    int b = row >> 11, s = row & 2047;
                    int hh = col >> 7, hd = col & 127;
                    size_t addr = (((size_t)(b * 16 + hh) * 2048 + s) << 7)
                                  + (((hd >> 3) ^ (s & 7)) << 3) + (hd & 7);
                    Qh[addr] = f2b(v);
                }
            }
    } else {
        // ---- KV projection: split-K 4, f32 reg-staged A, single-buffer ----
        int e = id - 512;
        int z = e >> 6, r = e & 63, isV = r & 1;
        int bm = (r >> 1) * 128, bn = isV * 128;
        const float* Atile = (isV ? value : key) + (size_t)bm * 2048;
        const us* Btile = Wkvt + (size_t)bn * 2048;
        const int kbeg = z * 512;
        const int arow = tid >> 1, h = tid & 1;
        const float* Ag = Atile + (size_t)arow * 2048 + h * 32;

        for (int kk = 0; kk < 8; kk++) {
            float4 pf[8];
            loadA_f32(Ag + kbeg + kk * 64, pf);    // overlaps prev MFMA phase
            __syncthreads();                       // buffer free
            writeA_f32(A0, pf, arow, h);
            dma_tile(Btile, kbeg + kk * 64, B0, tid);
            __syncthreads();                       // drain + publish
            frag_mfma(A0, B0, wm, wn, lm, quad, acc);
        }

        float* pp = part + (size_t)z * 1048576;
#pragma unroll
        for (int mi = 0; mi < 4; mi++)
#pragma unroll
            for (int ni = 0; ni < 4; ni++) {
                int col = bn + wn * 64 + ni * 16 + lm;
#pragma unroll
                for (int r = 0; r < 4; r++) {
                    int row = bm + wm * 64 + mi * 16 + quad * 4 + r;
                    pp[(size_t)row * 256 + col] = acc[mi][ni][r];
                }
            }
    }
}

// ---------------------------------------------------------------------------
// finish_wot: blocks [0,2048) transpose+cast Wo; [2048,6144) kv split-K reduce
__global__ void finish_wot(const float* __restrict__ part, const float* __restrict__ bk,
                           const float* __restrict__ bv, us* __restrict__ Kb,
                           us* __restrict__ Vt, const float* __restrict__ Wo,
                           us* __restrict__ Wot) {
    int b = blockIdx.x;
    if (b < 2048) {
        int id = b * 256 + threadIdx.x;
        int n = id & 2047, k0 = (id >> 11) * 8;
        us t8[8];
#pragma unroll
        for (int j = 0; j < 8; j++) t8[j] = f2b(Wo[(size_t)(k0 + j) * 2048 + n]);
        *(uint4*)&Wot[(size_t)n * 2048 + k0] = *(uint4*)t8;
    } else {
        int id = (b - 2048) * 256 + threadIdx.x;
        int row = id >> 8, n = id & 255;
        float s = part[id] + part[1048576 + id] + part[2097152 + id] + part[3145728 + id];
        int bb = row >> 11, t = row & 2047;
        if (n < 128) {
            int hd = n;
            s += bk[hd];
            Kb[((size_t)(bb * 2048 + t) << 7) + (((hd >> 3) ^ (t & 7)) << 3) + (hd & 7)] = f2b(s);
        } else {
            int hd = n - 128;
            s += bv[hd];
            size_t addr = (((size_t)(bb * 64 + (t >> 5)) * 128 + hd) << 5)
                          + ((((t >> 3) & 3) ^ ((hd >> 1) & 3)) << 3) + (t & 7);
            Vt[addr] = f2b(s);
        }
    }
}

// ---------------------------------------------------------------------------
// MQA flash attention v4 (round-3 verbatim): QBLK=128 (512 blocks, 2/CU),
// 4 waves 2x2. K fragments read directly from global (L2-resident) with
// 1-iter register prefetch; Q fragments direct from global (scale pre-folded
// in Qh). V double-buffered in LDS via gl_lds; Ps double-buffered; one
// barrier per KV-iteration.
__global__ __launch_bounds__(256, 2) void mqa_attn(
    const us* __restrict__ Qh, const us* __restrict__ Kb,
    const us* __restrict__ Vt, us* __restrict__ AO)
{
    __shared__ __align__(16) char smem[33792];
    us* Ps  = (us*)smem;                 // [0,16K): 2 x 8KB
    us* Vts = (us*)(smem + 16384);       // [16K,32K): 2 x 8KB
    float* Lb = (float*)(smem + 32768);  // [32K,33K): 256 floats

    const int tid  = threadIdx.x;
    const int lane = tid & 63;
    const int w    = tid >> 6;
    const int lm   = lane & 15;
    const int quad = lane >> 4;
    const int wm = w >> 1, wn = w & 1;   // wm: t/hd half, wn: q half (64 rows)
    const int q0 = blockIdx.x * 128;
    const int h  = blockIdx.y;
    const int b  = blockIdx.z;

    const us* Qtile = Qh + (((size_t)(b * 16 + h) * 2048 + q0) << 7);
    const us* Kbase = Kb + ((size_t)b * 2048 << 7);
    const us* Vbase = Vt + (size_t)b * 64 * 4096;

    // stage V(0) tile (8KB, 512 slots, 2 per thread)
#pragma unroll
    for (int i = 0; i < 2; i++) {
        int sl = w * 128 + i * 64 + lane;
        gl_lds16(Vbase + sl * 8, (char*)Vts + (w * 128 + i * 64) * 16);
    }

    // Q fragments direct from global (swizzled layout preserved by proj)
    bf16x8 qf[4][4];
#pragma unroll
    for (int nt = 0; nt < 4; nt++)
#pragma unroll
        for (int ks = 0; ks < 4; ks++) {
            int q = wn * 64 + nt * 16 + lm;
            int cp = (ks * 4 + quad) ^ (q & 7);
            qf[nt][ks] = *(const bf16x8*)&Qtile[q * 128 + cp * 8];
        }

    // K fragments for it=0, direct from global (same swizzle as LDS copy had)
    const int trow = wm * 16 + lm;       // wave's K row within 32-row tile
    bf16x8 kfc[4], kfn[4];
#pragma unroll
    for (int ks = 0; ks < 4; ks++) {
        int cp = (ks * 4 + quad) ^ (lm & 7);
        kfc[ks] = *(const bf16x8*)&Kbase[(size_t)trow * 128 + cp * 8];
    }

    __syncthreads();   // V(0) drained (also waits qf/kf loads)

    f32x4 oacc[4][4];
#pragma unroll
    for (int i = 0; i < 4; i++)
#pragma unroll
        for (int j = 0; j < 4; j++) oacc[i][j] = (f32x4){0.f, 0.f, 0.f, 0.f};
    float lsum[4] = {0.f, 0.f, 0.f, 0.f};

    for (int it = 0; it < 64; ++it) {
        const int p = it & 1;

        // K register-prefetch for it+1 (consumed next iteration; copy point
        // at loop end gives ~a full iteration of latency cover)
        if (it < 63) {
            const us* kg = Kbase + (size_t)(it + 1) * 4096 + (size_t)trow * 128;
#pragma unroll
            for (int ks = 0; ks < 4; ks++) {
                int cp = (ks * 4 + quad) ^ (lm & 7);
                kfn[ks] = *(const bf16x8*)&kg[cp * 8];
            }
        }

        // QK^T with current K fragments (pure register)
        f32x4 sacc[4];
#pragma unroll
        for (int nt = 0; nt < 4; nt++) sacc[nt] = (f32x4){0.f, 0.f, 0.f, 0.f};
        __builtin_amdgcn_s_setprio(1);
#pragma unroll
        for (int ks = 0; ks < 4; ks++) {
#pragma unroll
            for (int nt = 0; nt < 4; nt++)
                sacc[nt] = __builtin_amdgcn_mfma_f32_16x16x32_bf16(
                    kfc[ks], qf[nt][ks], sacc[nt], 0, 0, 0);
        }
        __builtin_amdgcn_s_setprio(0);

        // softmax (scale pre-folded into Q) -> Ps[p]
        us* Pw = Ps + p * 4096;
#pragma unroll
        for (int nt = 0; nt < 4; nt++) {
            int q = wn * 64 + nt * 16 + lm;
            float p0 = fexp2(sacc[nt][0]);
            float p1 = fexp2(sacc[nt][1]);
            float p2 = fexp2(sacc[nt][2]);
            float p3 = fexp2(sacc[nt][3]);
            lsum[nt] += (p0 + p1) + (p2 + p3);
            int tb = wm * 16 + quad * 4;
            int cp = (tb >> 3) ^ ((q >> 1) & 3);
            *(uint2*)&Pw[q * 32 + cp * 8 + (tb & 7)] = pack4(p0, p1, p2, p3);
        }

        __syncthreads();   // Ps[p] published; V prefetch (issued last iter) drained

        // V prefetch for it+1 into Vts[1-p] (last read at PV(it-1), which is
        // before barrier(it)); drains at barrier(it+1) before PV(it+1).
        if (it < 63) {
            const us* vg = Vbase + (it + 1) * 4096;
#pragma unroll
            for (int i = 0; i < 2; i++) {
                int sl = w * 128 + i * 64 + lane;
                gl_lds16(vg + sl * 8, (char*)Vts + (1 - p) * 8192 + (w * 128 + i * 64) * 16);
            }
        }

        const us* Vst = Vts + p * 4096;
        const us* Pr = Ps + p * 4096;
        bf16x8 vf[4], pfr[4];
#pragma unroll
        for (int mt = 0; mt < 4; mt++) {
            int hd = (wm * 4 + mt) * 16 + lm;
            int cp = quad ^ ((hd >> 1) & 3);
            vf[mt] = *(const bf16x8*)&Vst[hd * 32 + cp * 8];
        }
#pragma unroll
        for (int nt = 0; nt < 4; nt++) {
            int q = (wn * 4 + nt) * 16 + lm;
            int cp = quad ^ ((q >> 1) & 3);
            pfr[nt] = *(const bf16x8*)&Pr[q * 32 + cp * 8];
        }
        __builtin_amdgcn_s_setprio(1);
#pragma unroll
        for (int mt = 0; mt < 4; mt++)
#pragma unroll
            for (int nt = 0; nt < 4; nt++)
                oacc[mt][nt] = __builtin_amdgcn_mfma_f32_16x16x32_bf16(
                    vf[mt], pfr[nt], oacc[mt][nt], 0, 0, 0);
        __builtin_amdgcn_s_setprio(0);

        // rotate K prefetch registers (wait lands here, ~full iter after issue)
#pragma unroll
        for (int ks = 0; ks < 4; ks++) kfc[ks] = kfn[ks];
    }

#pragma unroll
    for (int nt = 0; nt < 4; nt++) {
        lsum[nt] += __shfl_xor(lsum[nt], 16);
        lsum[nt] += __shfl_xor(lsum[nt], 32);
    }
    if (quad == 0) {
#pragma unroll
        for (int nt = 0; nt < 4; nt++)
            Lb[wm * 128 + wn * 64 + nt * 16 + lm] = lsum[nt];
    }
    __syncthreads();

#pragma unroll
    for (int nt = 0; nt < 4; nt++) {
        int q = (wn * 4 + nt) * 16 + lm;
        float linv = 1.f / (Lb[q] + Lb[128 + q]);
#pragma unroll
        for (int mt = 0; mt < 4; mt++) {
            int hdb = (wm * 4 + mt) * 16 + quad * 4;
            uint2 u = pack4(oacc[mt][nt][0] * linv, oacc[mt][nt][1] * linv,
                            oacc[mt][nt][2] * linv, oacc[mt][nt][3] * linv);
            *(uint2*)&AO[((size_t)(b * 2048 + q0 + q)) * 2048 + h * 128 + hdb] = u;
        }
    }
}

// ---------------------------------------------------------------------------
// output projection: AO bf16 @ Wot^T + bo -> f32, single-buffered pure-DMA.
// XCD-chunked remap over the FLAT 512-tile index (blockIdx.y*16 + blockIdx.x)
// -- round-7 bug was remapping blockIdx.x alone and dropping blockIdx.y.
__global__ __launch_bounds__(256, 4) void oproj(
    const us* __restrict__ AO, const us* __restrict__ Wot,
    const float* __restrict__ bo, float* __restrict__ out)
{
    __shared__ __align__(16) us A0[128 * 64];
    __shared__ __align__(16) us B0[128 * 64];

    const int tid = threadIdx.x;
    const int lane = tid & 63, w = tid >> 6, lm = lane & 15, quad = lane >> 4;
    const int wm = w >> 1, wn = w & 1;
    // flat tile id in [0,512), then bijective XCD-chunk remap (512 % 8 == 0)
    const int tile = blockIdx.y * 16 + blockIdx.x;
    const int nid = (tile & 7) * 64 + (tile >> 3);
    const int bn = (nid & 15) * 128, bm = (nid >> 4) * 128;
    const us* Atile = AO + (size_t)bm * 2048;
    const us* Btile = Wot + (size_t)bn * 2048;

    f32x4 acc[4][4];
#pragma unroll
    for (int i = 0; i < 4; i++)
#pragma unroll
        for (int j = 0; j < 4; j++) acc[i][j] = (f32x4){0.f, 0.f, 0.f, 0.f};

    for (int kk = 0; kk < 32; kk++) {
        __syncthreads();                       // buffer free
        dma_tile(Atile, kk * 64, A0, tid);
        dma_tile(Btile, kk * 64, B0, tid);
        __syncthreads();                       // drain + publish
        frag_mfma(A0, B0, wm, wn, lm, quad, acc);
    }

#pragma unroll
    for (int mi = 0; mi < 4; mi++)
#pragma unroll
        for (int ni = 0; ni < 4; ni++) {
            int col = bn + wn * 64 + ni * 16 + lm;
            float bv = bo[col];
#pragma unroll
            for (int r = 0; r < 4; r++) {
                int row = bm + wm * 64 + mi * 16 + quad * 4 + r;
                out[(size_t)row * 2048 + col] = acc[mi][ni][r] + bv;
            }
        }
}

// ---------------------------------------------------------------------------
extern "C" void kernel_launch(void* const* d_in, const int* in_sizes, int n_in,
                              void* d_out, int out_size, void* d_ws, size_t ws_size,
                              hipStream_t stream) {
    const float* query = (const float*)d_in[0];
    const float* key   = (const float*)d_in[1];
    const float* value = (const float*)d_in[2];
    const float* Wq = (const float*)d_in[3];
    const float* bq = (const float*)d_in[4];
    const float* Wk = (const float*)d_in[5];
    const float* bk = (const float*)d_in[6];
    const float* Wv = (const float*)d_in[7];
    const float* bv = (const float*)d_in[8];
    const float* Wo = (const float*)d_in[9];
    const float* bo = (const float*)d_in[10];
    float* out = (float*)d_out;

    char* ws = (char*)d_ws;
    us*    Wqt  = (us*)ws;                  //  8.39MB (reused for Wot)
    us*    Wot  = Wqt;
    us*    Wkvt = (us*)(ws + 8388608);      //  1.05MB
    us*    Qh   = (us*)(ws + 9437184);      // 16.78MB
    float* part = (float*)(ws + 26214400);  // 16.78MB (reused for AO)
    us*    AO   = (us*)part;
    us*    Kb   = (us*)(ws + 42991616);     //  1.05MB
    us*    Vtb  = (us*)(ws + 44040192);     //  1.05MB
    us*    qbf  = (us*)(ws + 45088768);     // 16.78MB bf16 query (row-major)

    dim3 blk(256);
    tcast3<<<6400, blk, 0, stream>>>(Wq, Wk, Wv, query, Wqt, Wkvt, qbf);
    proj_qkv<<<768, blk, 0, stream>>>(key, value, qbf, Wqt, Wkvt, bq, Qh, part);
    finish_wot<<<6144, blk, 0, stream>>>(part, bk, bv, Kb, Vtb, Wo, Wot);
    mqa_attn<<<dim3(16, 16, 2), blk, 0, stream>>>(Qh, Kb, Vtb, AO);
    oproj<<<dim3(16, 32), blk, 0, stream>>>(AO, Wot, bo, out);
}